// Round 1
// baseline (1586.309 us; speedup 1.0000x reference)
//
#include <hip/hip_runtime.h>

typedef __attribute__((ext_vector_type(8))) short short8;
typedef __attribute__((ext_vector_type(4))) float f32x4;

static __device__ __forceinline__ float b2f(unsigned short u) {
  return __uint_as_float(((unsigned int)u) << 16);
}
static __device__ __forceinline__ unsigned short f2bs(float f) {
  unsigned int u = __float_as_uint(f);
  u = u + 0x7FFFu + ((u >> 16) & 1u);   // RNE (no NaN inputs here)
  return (unsigned short)(u >> 16);
}

enum { EPI_F32_SUMSQ = 0, EPI_BF16_SUMSQ = 1, EPI_BF16 = 2, EPI_F32_RESID = 3 };

// C[M,N] = A[M,K] @ B[N,K]^T  (both K-contiguous). bf16 MFMA 16x16x32.
// BM x BN tile, BK=64, 4 waves (2x2), wave tile (BM/2)x(BN/2).
template<int BM, int BN, bool AF32, int EPI>
__global__ __launch_bounds__(256, 2) void gemm_bt(
    const void* __restrict__ Av, const short* __restrict__ B, void* __restrict__ Cv,
    const float* __restrict__ bias, const float* __restrict__ resid,
    float* __restrict__ sumsq,
    long lda, long ldb, long ldc, int K, float escale,
    long aZ, long bZ, long cZ, int biasZ)
{
  constexpr int BK = 64;
  constexpr int WM = BM / 2, WN = BN / 2, MR = WM / 16, NR = WN / 16;
  __shared__ __align__(16) short As[BM * BK];
  __shared__ __align__(16) short Bs[BN * BK];
  const int t = threadIdx.x;
  const int z = blockIdx.z;
  const long row0 = (long)blockIdx.x * BM;
  const long col0 = (long)blockIdx.y * BN;
  const int wave = t >> 6, lane = t & 63;
  const int wr = wave >> 1, wc = wave & 1;
  const int lr = lane & 15, lg = lane >> 4;
  const short* Bz = B + (size_t)z * bZ;

  const f32x4 zero4 = {0.f, 0.f, 0.f, 0.f};
  f32x4 acc[MR][NR];
  #pragma unroll
  for (int m = 0; m < MR; ++m)
    #pragma unroll
    for (int n = 0; n < NR; ++n) acc[m][n] = zero4;

  for (int k0 = 0; k0 < K; k0 += BK) {
    if constexpr (AF32) {
      const float* A = (const float*)Av + (size_t)z * aZ;
      #pragma unroll
      for (int r = 0; r < BM / 32; ++r) {
        int e = r * 2048 + t * 8;
        int row = e >> 6, col = e & 63;
        const float* src = A + (size_t)(row0 + row) * lda + k0 + col;
        float4 p = *(const float4*)src;
        float4 q = *(const float4*)(src + 4);
        short8 o;
        o[0] = (short)f2bs(p.x); o[1] = (short)f2bs(p.y);
        o[2] = (short)f2bs(p.z); o[3] = (short)f2bs(p.w);
        o[4] = (short)f2bs(q.x); o[5] = (short)f2bs(q.y);
        o[6] = (short)f2bs(q.z); o[7] = (short)f2bs(q.w);
        *(short8*)&As[row * BK + col] = o;
      }
    } else {
      const short* A = (const short*)Av + (size_t)z * aZ;
      #pragma unroll
      for (int r = 0; r < BM / 32; ++r) {
        int e = r * 2048 + t * 8;
        int row = e >> 6, col = e & 63;
        *(short8*)&As[row * BK + col] =
            *(const short8*)(A + (size_t)(row0 + row) * lda + k0 + col);
      }
    }
    #pragma unroll
    for (int r = 0; r < BN / 32; ++r) {
      int e = r * 2048 + t * 8;
      int row = e >> 6, col = e & 63;
      *(short8*)&Bs[row * BK + col] =
          *(const short8*)(Bz + (size_t)(col0 + row) * ldb + k0 + col);
    }
    __syncthreads();
    #pragma unroll
    for (int kk = 0; kk < 2; ++kk) {
      short8 a[MR], b[NR];
      #pragma unroll
      for (int m = 0; m < MR; ++m)
        a[m] = *(const short8*)&As[(wr * WM + m * 16 + lr) * BK + kk * 32 + lg * 8];
      #pragma unroll
      for (int n = 0; n < NR; ++n)
        b[n] = *(const short8*)&Bs[(wc * WN + n * 16 + lr) * BK + kk * 32 + lg * 8];
      #pragma unroll
      for (int m = 0; m < MR; ++m)
        #pragma unroll
        for (int n = 0; n < NR; ++n)
          acc[m][n] = __builtin_amdgcn_mfma_f32_16x16x32_bf16(a[m], b[n], acc[m][n], 0, 0, 0);
    }
    __syncthreads();
  }

  const float* biasz = bias ? (bias + (size_t)z * biasZ) : nullptr;
  float* Cf = (float*)Cv;
  unsigned short* Cb = (unsigned short*)Cv;
  #pragma unroll
  for (int m = 0; m < MR; ++m) {
    #pragma unroll
    for (int i = 0; i < 4; ++i) {
      long row = row0 + wr * WM + m * 16 + lg * 4 + i;
      float sq = 0.f;
      #pragma unroll
      for (int n = 0; n < NR; ++n) {
        long col = col0 + wc * WN + n * 16 + lr;
        float v = acc[m][n][i];
        if (biasz) v += biasz[col];
        v *= escale;
        size_t ci = (size_t)z * cZ + (size_t)row * ldc + col;
        if constexpr (EPI == EPI_F32_RESID) {
          v += resid[(size_t)row * ldc + col];
          Cf[ci] = v;
        } else if constexpr (EPI == EPI_F32_SUMSQ) {
          Cf[ci] = v;
        } else {
          Cb[ci] = f2bs(v);
        }
        sq += v * v;
      }
      if constexpr (EPI == EPI_F32_SUMSQ || EPI == EPI_BF16_SUMSQ) {
        #pragma unroll
        for (int off = 1; off < 16; off <<= 1) sq += __shfl_xor(sq, off);
        if (lr == 0) atomicAdd(&sumsq[row], sq);
      }
    }
  }
}

__global__ __launch_bounds__(256) void f2b_kernel(const float* __restrict__ s,
                                                  unsigned short* __restrict__ d, long n) {
  long i = (long)blockIdx.x * 256 + threadIdx.x;
  if (i < n) d[i] = f2bs(s[i]);
}

// WkT[h][n][j] = Wk[h*64+j][n],  Wk = in_proj_w rows 768..1535
__global__ __launch_bounds__(256) void wkT_kernel(const float* __restrict__ ipw,
                                                  unsigned short* __restrict__ d) {
  long i = (long)blockIdx.x * 256 + threadIdx.x;
  if (i < 589824) {
    int h = (int)(i / 49152), r = (int)(i % 49152);
    int nn = r >> 6, j = r & 63;
    d[i] = f2bs(ipw[(size_t)(768 + h * 64 + j) * 768 + nn]);
  }
}

__global__ __launch_bounds__(256) void invnorm_kernel(float* s, int n) {
  int i = blockIdx.x * 256 + threadIdx.x;
  if (i < n) s[i] = 1.f / (sqrtf(s[i]) + 1e-6f);
}

__global__ __launch_bounds__(256) void xqnorm_kernel(const float* __restrict__ raw,
                                                     const float* __restrict__ invn,
                                                     float* __restrict__ xf,
                                                     unsigned short* __restrict__ xb) {
  long i = (long)blockIdx.x * 256 + threadIdx.x;  // 8192*768
  int row = (int)(i / 768);
  float v = raw[i] * invn[row];
  xf[i] = v;
  xb[i] = f2bs(v);
}

// Per-token fused: scores = (qk . z)*invn -> softmax_w -> a = attn*invn -> u = a @ z
// u may alias qk (per-block slice read fully into LDS before write).
__global__ __launch_bounds__(256) void attn_kernel(
    const unsigned short* __restrict__ z, const unsigned short* __restrict__ qk,
    const float* __restrict__ invn, unsigned short* __restrict__ u)
{
  __shared__ __align__(16) unsigned short zl[16 * 768];
  __shared__ __align__(16) unsigned short ql[12 * 768];
  __shared__ float sl[192];
  __shared__ float al[192];
  __shared__ float il[16];
  const int t = threadIdx.x;
  const long m = blockIdx.x;
  const short8* zsrc = (const short8*)(z + m * 12288);
  short8* zdst = (short8*)zl;
  #pragma unroll
  for (int r = 0; r < 6; ++r) zdst[r * 256 + t] = zsrc[r * 256 + t];
  const short8* qsrc = (const short8*)(qk + m * 9216);
  short8* qdst = (short8*)ql;
  for (int i = t; i < 1152; i += 256) qdst[i] = qsrc[i];
  if (t < 16) il[t] = invn[m * 16 + t];
  __syncthreads();
  const int wave = t >> 6, lane = t & 63;
  for (int s = 0; s < 48; ++s) {
    const int di = wave * 48 + s;
    const int h = di >> 4, w = di & 15;
    float acc = 0.f;
    #pragma unroll
    for (int j = 0; j < 12; ++j)
      acc += b2f(ql[h * 768 + j * 64 + lane]) * b2f(zl[w * 768 + j * 64 + lane]);
    #pragma unroll
    for (int off = 1; off < 64; off <<= 1) acc += __shfl_xor(acc, off);
    if (lane == 0) sl[di] = acc * il[w];
  }
  __syncthreads();
  if (t < 12) {
    float mx = -1e30f;
    #pragma unroll
    for (int w = 0; w < 16; ++w) mx = fmaxf(mx, sl[t * 16 + w]);
    float sum = 0.f;
    float e[16];
    #pragma unroll
    for (int w = 0; w < 16; ++w) { e[w] = expf(sl[t * 16 + w] - mx); sum += e[w]; }
    float inv = 1.f / sum;
    #pragma unroll
    for (int w = 0; w < 16; ++w) al[t * 16 + w] = e[w] * inv * il[w];
  }
  __syncthreads();
  for (int i = t; i < 9216; i += 256) {
    const int h = i / 768, d = i % 768;
    float a0 = 0.f;
    #pragma unroll
    for (int w = 0; w < 16; ++w) a0 += al[h * 16 + w] * b2f(zl[w * 768 + d]);
    u[m * 9216 + i] = f2bs(a0);
  }
}

__global__ __launch_bounds__(256) void ln_kernel(const float* __restrict__ R,
                                                 const float* __restrict__ w,
                                                 const float* __restrict__ b,
                                                 float* __restrict__ out) {
  const long row = blockIdx.x;
  const int t = threadIdx.x;
  const float* rr = R + row * 768;
  float v0 = rr[t], v1 = rr[t + 256], v2 = rr[t + 512];
  float s = v0 + v1 + v2;
  #pragma unroll
  for (int off = 1; off < 64; off <<= 1) s += __shfl_xor(s, off);
  __shared__ float ps[4];
  __shared__ float ps2[4];
  const int wave = t >> 6, lane = t & 63;
  if (lane == 0) ps[wave] = s;
  __syncthreads();
  const float mean = (ps[0] + ps[1] + ps[2] + ps[3]) * (1.f / 768.f);
  const float d0 = v0 - mean, d1 = v1 - mean, d2 = v2 - mean;
  float q = d0 * d0 + d1 * d1 + d2 * d2;
  #pragma unroll
  for (int off = 1; off < 64; off <<= 1) q += __shfl_xor(q, off);
  if (lane == 0) ps2[wave] = q;
  __syncthreads();
  const float var = (ps2[0] + ps2[1] + ps2[2] + ps2[3]) * (1.f / 768.f);
  const float rs = rsqrtf(var + 1e-6f);
  float* oo = out + row * 768;
  oo[t]       = d0 * rs * w[t]       + b[t];
  oo[t + 256] = d1 * rs * w[t + 256] + b[t + 256];
  oo[t + 512] = d2 * rs * w[t + 512] + b[t + 512];
}

extern "C" void kernel_launch(void* const* d_in, const int* in_sizes, int n_in,
                              void* d_out, int out_size, void* d_ws, size_t ws_size,
                              hipStream_t stream) {
  const float* x   = (const float*)d_in[0];   // (8,1024,1536)
  const float* y   = (const float*)d_in[1];   // (8,16384,1024)
  const float* Wx  = (const float*)d_in[2];   // (768,1536)
  const float* bx  = (const float*)d_in[3];
  const float* Wy  = (const float*)d_in[4];   // (768,1024)
  const float* by  = (const float*)d_in[5];
  const float* ipw = (const float*)d_in[6];   // (2304,768)
  const float* ipb = (const float*)d_in[7];
  const float* Wo  = (const float*)d_in[8];   // (768,768)
  const float* ob  = (const float*)d_in[9];
  const float* lnw = (const float*)d_in[10];
  const float* lnb = (const float*)d_in[11];
  float* out = (float*)d_out;

  char* ws = (char*)d_ws;
  size_t off = 0;
  auto alloc = [&](size_t bytes) {
    void* p = ws + off;
    off += (bytes + 4095) & ~(size_t)4095;
    return p;
  };
  unsigned short* Wx_b  = (unsigned short*)alloc(768L * 1536 * 2);
  unsigned short* Wy_b  = (unsigned short*)alloc(768L * 1024 * 2);
  unsigned short* Wq_b  = (unsigned short*)alloc(768L * 768 * 2);
  unsigned short* WkT_b = (unsigned short*)alloc(768L * 768 * 2);
  unsigned short* Wv_b  = (unsigned short*)alloc(768L * 768 * 2);
  unsigned short* Wo_b  = (unsigned short*)alloc(768L * 768 * 2);
  float* ssx    = (float*)alloc(8192L * 4);          // sumsq -> invnorm (x path)
  float* ssy    = (float*)alloc(131072L * 4);        // sumsq -> invnorm (y path)
  float* xq_raw = (float*)alloc(8192L * 768 * 4);    // reused as r (residual) later
  float* xq_f   = (float*)alloc(8192L * 768 * 4);
  unsigned short* xq_b = (unsigned short*)alloc(8192L * 768 * 2);
  unsigned short* z_b  = (unsigned short*)alloc(131072L * 768 * 2);
  unsigned short* q_b  = (unsigned short*)alloc(8192L * 768 * 2);
  unsigned short* qk_b = (unsigned short*)alloc(8192L * 9216 * 2);  // also u (aliased)
  unsigned short* o_b  = (unsigned short*)alloc(8192L * 768 * 2);
  float* r_f = xq_raw;
  (void)ws_size; (void)in_sizes; (void)n_in; (void)out_size;

  hipMemsetAsync(ssx, 0, 8192L * 4, stream);
  hipMemsetAsync(ssy, 0, 131072L * 4, stream);

  f2b_kernel<<<4608, 256, 0, stream>>>(Wx, Wx_b, 768L * 1536);
  f2b_kernel<<<3072, 256, 0, stream>>>(Wy, Wy_b, 768L * 1024);
  f2b_kernel<<<2304, 256, 0, stream>>>(ipw, Wq_b, 589824);               // Wq
  wkT_kernel<<<2304, 256, 0, stream>>>(ipw, WkT_b);                      // Wk^T per head
  f2b_kernel<<<2304, 256, 0, stream>>>(ipw + 2 * 589824, Wv_b, 589824);  // Wv
  f2b_kernel<<<2304, 256, 0, stream>>>(Wo, Wo_b, 589824);

  // xq_raw = x @ Wx^T + bx   (+ row sumsq)
  gemm_bt<128, 128, true, EPI_F32_SUMSQ><<<dim3(64, 6, 1), 256, 0, stream>>>(
      x, (const short*)Wx_b, xq_raw, bx, nullptr, ssx,
      1536, 1536, 768, 1536, 1.f, 0, 0, 0, 0);
  invnorm_kernel<<<32, 256, 0, stream>>>(ssx, 8192);
  xqnorm_kernel<<<24576, 256, 0, stream>>>(xq_raw, ssx, xq_f, xq_b);

  // z = y @ Wy^T + by (bf16) + row sumsq -> invnorm (l2n applied downstream)
  gemm_bt<128, 128, true, EPI_BF16_SUMSQ><<<dim3(1024, 6, 1), 256, 0, stream>>>(
      y, (const short*)Wy_b, z_b, by, nullptr, ssy,
      1024, 1024, 768, 1024, 1.f, 0, 0, 0, 0);
  invnorm_kernel<<<512, 256, 0, stream>>>(ssy, 131072);

  // q = xq @ Wq^T + bq
  gemm_bt<128, 128, false, EPI_BF16><<<dim3(64, 6, 1), 256, 0, stream>>>(
      xq_b, (const short*)Wq_b, q_b, ipb, nullptr, nullptr,
      768, 768, 768, 768, 1.f, 0, 0, 0, 0);

  // qk[m,h,:] = scale * q[m,h*64:+64] @ WkT[h]   (bk dropped: softmax-invariant)
  gemm_bt<128, 128, false, EPI_BF16><<<dim3(64, 6, 12), 256, 0, stream>>>(
      q_b, (const short*)WkT_b, qk_b, nullptr, nullptr, nullptr,
      768, 64, 9216, 64, 0.125f, 64, 49152, 768, 0);

  // fused scores/softmax/u  (u overwrites qk slice per token)
  attn_kernel<<<8192, 256, 0, stream>>>(z_b, qk_b, ssy, qk_b);

  // o[:,h*64:+64] = u[:,h,:] @ Wv_h^T + bv_h
  gemm_bt<128, 64, false, EPI_BF16><<<dim3(64, 1, 12), 256, 0, stream>>>(
      qk_b, (const short*)Wv_b, o_b, ipb + 1536, nullptr, nullptr,
      9216, 768, 768, 768, 1.f, 768, 49152, 64, 64);

  // r = o @ out_w^T + out_b + xq
  gemm_bt<128, 128, false, EPI_F32_RESID><<<dim3(64, 6, 1), 256, 0, stream>>>(
      o_b, (const short*)Wo_b, r_f, ob, xq_f, nullptr,
      768, 768, 768, 768, 1.f, 0, 0, 0, 0);

  ln_kernel<<<8192, 256, 0, stream>>>(r_f, lnw, lnb, out);
}

// Round 2
// 1332.193 us; speedup vs baseline: 1.1907x; 1.1907x over previous
//
#include <hip/hip_runtime.h>

typedef __attribute__((ext_vector_type(8))) short short8;
typedef __attribute__((ext_vector_type(4))) float f32x4;

static __device__ __forceinline__ float b2f(unsigned short u) {
  return __uint_as_float(((unsigned int)u) << 16);
}
static __device__ __forceinline__ unsigned short f2bs(float f) {
  unsigned int u = __float_as_uint(f);
  u = u + 0x7FFFu + ((u >> 16) & 1u);   // RNE (no NaN inputs here)
  return (unsigned short)(u >> 16);
}

enum { EPI_F32_SUMSQ = 0, EPI_BF16_SUMSQ = 1, EPI_BF16 = 2, EPI_F32_RESID = 3 };

// C[M,N] = A[M,K] @ B[N,K]^T  (both K-contiguous). bf16 MFMA 16x16x32.
// BM x BN tile, BK=64, 4 waves (2x2), wave tile (BM/2)x(BN/2).
// LDS layout XOR-swizzled: shorts index col ^ ((row&7)<<3)  (T2, fixes the
// 16-way conflict of stride-128B row reads).
template<int BM, int BN, bool AF32, int EPI, bool SWAPXY>
__global__ __launch_bounds__(256, 4) void gemm_bt(
    const void* __restrict__ Av, const short* __restrict__ B, void* __restrict__ Cv,
    const float* __restrict__ bias, const float* __restrict__ resid,
    float* __restrict__ sumsq,
    long lda, long ldb, long ldc, int K, float escale,
    long aZ, long bZ, long cZ, int biasZ)
{
  constexpr int BK = 64;
  constexpr int WM = BM / 2, WN = BN / 2, MR = WM / 16, NR = WN / 16;
  __shared__ __align__(16) short As[BM * BK];
  __shared__ __align__(16) short Bs[BN * BK];
  const int t = threadIdx.x;
  const int z = blockIdx.z;
  const long row0 = (long)(SWAPXY ? blockIdx.y : blockIdx.x) * BM;
  const long col0 = (long)(SWAPXY ? blockIdx.x : blockIdx.y) * BN;
  const int wave = t >> 6, lane = t & 63;
  const int wr = wave >> 1, wc = wave & 1;
  const int lr = lane & 15, lg = lane >> 4;
  const short* Bz = B + (size_t)z * bZ;

  const f32x4 zero4 = {0.f, 0.f, 0.f, 0.f};
  f32x4 acc[MR][NR];
  #pragma unroll
  for (int m = 0; m < MR; ++m)
    #pragma unroll
    for (int n = 0; n < NR; ++n) acc[m][n] = zero4;

  for (int k0 = 0; k0 < K; k0 += BK) {
    if constexpr (AF32) {
      const float* A = (const float*)Av + (size_t)z * aZ;
      #pragma unroll
      for (int r = 0; r < BM / 32; ++r) {
        int e = r * 2048 + t * 8;
        int row = e >> 6, col = e & 63;
        const float* src = A + (size_t)(row0 + row) * lda + k0 + col;
        float4 p = *(const float4*)src;
        float4 q = *(const float4*)(src + 4);
        short8 o;
        o[0] = (short)f2bs(p.x); o[1] = (short)f2bs(p.y);
        o[2] = (short)f2bs(p.z); o[3] = (short)f2bs(p.w);
        o[4] = (short)f2bs(q.x); o[5] = (short)f2bs(q.y);
        o[6] = (short)f2bs(q.z); o[7] = (short)f2bs(q.w);
        *(short8*)&As[row * BK + (col ^ ((row & 7) << 3))] = o;
      }
    } else {
      const short* A = (const short*)Av + (size_t)z * aZ;
      #pragma unroll
      for (int r = 0; r < BM / 32; ++r) {
        int e = r * 2048 + t * 8;
        int row = e >> 6, col = e & 63;
        *(short8*)&As[row * BK + (col ^ ((row & 7) << 3))] =
            *(const short8*)(A + (size_t)(row0 + row) * lda + k0 + col);
      }
    }
    #pragma unroll
    for (int r = 0; r < BN / 32; ++r) {
      int e = r * 2048 + t * 8;
      int row = e >> 6, col = e & 63;
      *(short8*)&Bs[row * BK + (col ^ ((row & 7) << 3))] =
          *(const short8*)(Bz + (size_t)(col0 + row) * ldb + k0 + col);
    }
    __syncthreads();
    #pragma unroll
    for (int kk = 0; kk < 2; ++kk) {
      short8 a[MR], b[NR];
      #pragma unroll
      for (int m = 0; m < MR; ++m) {
        int row = wr * WM + m * 16 + lr, col = kk * 32 + lg * 8;
        a[m] = *(const short8*)&As[row * BK + (col ^ ((row & 7) << 3))];
      }
      #pragma unroll
      for (int n = 0; n < NR; ++n) {
        int row = wc * WN + n * 16 + lr, col = kk * 32 + lg * 8;
        b[n] = *(const short8*)&Bs[row * BK + (col ^ ((row & 7) << 3))];
      }
      #pragma unroll
      for (int m = 0; m < MR; ++m)
        #pragma unroll
        for (int n = 0; n < NR; ++n)
          acc[m][n] = __builtin_amdgcn_mfma_f32_16x16x32_bf16(a[m], b[n], acc[m][n], 0, 0, 0);
    }
    __syncthreads();
  }

  const float* biasz = bias ? (bias + (size_t)z * biasZ) : nullptr;
  float* Cf = (float*)Cv;
  unsigned short* Cb = (unsigned short*)Cv;
  #pragma unroll
  for (int m = 0; m < MR; ++m) {
    #pragma unroll
    for (int i = 0; i < 4; ++i) {
      long row = row0 + wr * WM + m * 16 + lg * 4 + i;
      float sq = 0.f;
      #pragma unroll
      for (int n = 0; n < NR; ++n) {
        long col = col0 + wc * WN + n * 16 + lr;
        float v = acc[m][n][i];
        if (biasz) v += biasz[col];
        v *= escale;
        size_t ci = (size_t)z * cZ + (size_t)row * ldc + col;
        if constexpr (EPI == EPI_F32_RESID) {
          v += resid[(size_t)row * ldc + col];
          Cf[ci] = v;
        } else if constexpr (EPI == EPI_F32_SUMSQ) {
          Cf[ci] = v;
        } else {
          Cb[ci] = f2bs(v);
        }
        sq += v * v;
      }
      if constexpr (EPI == EPI_F32_SUMSQ || EPI == EPI_BF16_SUMSQ) {
        #pragma unroll
        for (int off = 1; off < 16; off <<= 1) sq += __shfl_xor(sq, off);
        if (lr == 0) atomicAdd(&sumsq[row], sq);
      }
    }
  }
}

__global__ __launch_bounds__(256) void f2b_kernel(const float* __restrict__ s,
                                                  unsigned short* __restrict__ d, long n) {
  long i = (long)blockIdx.x * 256 + threadIdx.x;
  if (i < n) d[i] = f2bs(s[i]);
}

// WkT[h][n][j] = Wk[h*64+j][n],  Wk = in_proj_w rows 768..1535
__global__ __launch_bounds__(256) void wkT_kernel(const float* __restrict__ ipw,
                                                  unsigned short* __restrict__ d) {
  long i = (long)blockIdx.x * 256 + threadIdx.x;
  if (i < 589824) {
    int h = (int)(i / 49152), r = (int)(i % 49152);
    int nn = r >> 6, j = r & 63;
    d[i] = f2bs(ipw[(size_t)(768 + h * 64 + j) * 768 + nn]);
  }
}

__global__ __launch_bounds__(256) void invnorm_kernel(float* s, int n) {
  int i = blockIdx.x * 256 + threadIdx.x;
  if (i < n) s[i] = 1.f / (sqrtf(s[i]) + 1e-6f);
}

__global__ __launch_bounds__(256) void xqnorm_kernel(const float* __restrict__ raw,
                                                     const float* __restrict__ invn,
                                                     float* __restrict__ xf,
                                                     unsigned short* __restrict__ xb) {
  long i = (long)blockIdx.x * 256 + threadIdx.x;  // 8192*768
  int row = (int)(i / 768);
  float v = raw[i] * invn[row];
  xf[i] = v;
  xb[i] = f2bs(v);
}

// Per-token fused: scores = (qk . z)*invn -> softmax_w -> a = attn*invn -> u = a @ z
// u may alias qk (per-block slice read fully into LDS before write).
__global__ __launch_bounds__(256) void attn_kernel(
    const unsigned short* __restrict__ z, const unsigned short* __restrict__ qk,
    const float* __restrict__ invn, unsigned short* __restrict__ u)
{
  __shared__ __align__(16) unsigned short zl[16 * 768];
  __shared__ __align__(16) unsigned short ql[12 * 768];
  __shared__ float sl[192];
  __shared__ float al[192];
  __shared__ float il[16];
  const int t = threadIdx.x;
  const long m = blockIdx.x;
  const short8* zsrc = (const short8*)(z + m * 12288);
  short8* zdst = (short8*)zl;
  #pragma unroll
  for (int r = 0; r < 6; ++r) zdst[r * 256 + t] = zsrc[r * 256 + t];
  const short8* qsrc = (const short8*)(qk + m * 9216);
  short8* qdst = (short8*)ql;
  for (int i = t; i < 1152; i += 256) qdst[i] = qsrc[i];
  if (t < 16) il[t] = invn[m * 16 + t];
  __syncthreads();
  const int wave = t >> 6, lane = t & 63;
  for (int s = 0; s < 48; ++s) {
    const int di = wave * 48 + s;
    const int h = di >> 4, w = di & 15;
    float acc = 0.f;
    #pragma unroll
    for (int j = 0; j < 12; ++j)
      acc += b2f(ql[h * 768 + j * 64 + lane]) * b2f(zl[w * 768 + j * 64 + lane]);
    #pragma unroll
    for (int off = 1; off < 64; off <<= 1) acc += __shfl_xor(acc, off);
    if (lane == 0) sl[di] = acc * il[w];
  }
  __syncthreads();
  if (t < 12) {
    float mx = -1e30f;
    #pragma unroll
    for (int w = 0; w < 16; ++w) mx = fmaxf(mx, sl[t * 16 + w]);
    float sum = 0.f;
    float e[16];
    #pragma unroll
    for (int w = 0; w < 16; ++w) { e[w] = expf(sl[t * 16 + w] - mx); sum += e[w]; }
    float inv = 1.f / sum;
    #pragma unroll
    for (int w = 0; w < 16; ++w) al[t * 16 + w] = e[w] * inv * il[w];
  }
  __syncthreads();
  for (int i = t; i < 9216; i += 256) {
    const int h = i / 768, d = i % 768;
    float a0 = 0.f;
    #pragma unroll
    for (int w = 0; w < 16; ++w) a0 += al[h * 16 + w] * b2f(zl[w * 768 + d]);
    u[m * 9216 + i] = f2bs(a0);
  }
}

__global__ __launch_bounds__(256) void ln_kernel(const float* __restrict__ R,
                                                 const float* __restrict__ w,
                                                 const float* __restrict__ b,
                                                 float* __restrict__ out) {
  const long row = blockIdx.x;
  const int t = threadIdx.x;
  const float* rr = R + row * 768;
  float v0 = rr[t], v1 = rr[t + 256], v2 = rr[t + 512];
  float s = v0 + v1 + v2;
  #pragma unroll
  for (int off = 1; off < 64; off <<= 1) s += __shfl_xor(s, off);
  __shared__ float ps[4];
  __shared__ float ps2[4];
  const int wave = t >> 6, lane = t & 63;
  if (lane == 0) ps[wave] = s;
  __syncthreads();
  const float mean = (ps[0] + ps[1] + ps[2] + ps[3]) * (1.f / 768.f);
  const float d0 = v0 - mean, d1 = v1 - mean, d2 = v2 - mean;
  float q = d0 * d0 + d1 * d1 + d2 * d2;
  #pragma unroll
  for (int off = 1; off < 64; off <<= 1) q += __shfl_xor(q, off);
  if (lane == 0) ps2[wave] = q;
  __syncthreads();
  const float var = (ps2[0] + ps2[1] + ps2[2] + ps2[3]) * (1.f / 768.f);
  const float rs = rsqrtf(var + 1e-6f);
  float* oo = out + row * 768;
  oo[t]       = d0 * rs * w[t]       + b[t];
  oo[t + 256] = d1 * rs * w[t + 256] + b[t + 256];
  oo[t + 512] = d2 * rs * w[t + 512] + b[t + 512];
}

extern "C" void kernel_launch(void* const* d_in, const int* in_sizes, int n_in,
                              void* d_out, int out_size, void* d_ws, size_t ws_size,
                              hipStream_t stream) {
  const float* x   = (const float*)d_in[0];   // (8,1024,1536)
  const float* y   = (const float*)d_in[1];   // (8,16384,1024)
  const float* Wx  = (const float*)d_in[2];   // (768,1536)
  const float* bx  = (const float*)d_in[3];
  const float* Wy  = (const float*)d_in[4];   // (768,1024)
  const float* by  = (const float*)d_in[5];
  const float* ipw = (const float*)d_in[6];   // (2304,768)
  const float* ipb = (const float*)d_in[7];
  const float* Wo  = (const float*)d_in[8];   // (768,768)
  const float* ob  = (const float*)d_in[9];
  const float* lnw = (const float*)d_in[10];
  const float* lnb = (const float*)d_in[11];
  float* out = (float*)d_out;

  char* ws = (char*)d_ws;
  size_t off = 0;
  auto alloc = [&](size_t bytes) {
    void* p = ws + off;
    off += (bytes + 4095) & ~(size_t)4095;
    return p;
  };
  unsigned short* Wx_b  = (unsigned short*)alloc(768L * 1536 * 2);
  unsigned short* Wy_b  = (unsigned short*)alloc(768L * 1024 * 2);
  unsigned short* Wq_b  = (unsigned short*)alloc(768L * 768 * 2);
  unsigned short* WkT_b = (unsigned short*)alloc(768L * 768 * 2);
  unsigned short* Wv_b  = (unsigned short*)alloc(768L * 768 * 2);
  unsigned short* Wo_b  = (unsigned short*)alloc(768L * 768 * 2);
  float* ssx    = (float*)alloc(8192L * 4);          // sumsq -> invnorm (x path)
  float* ssy    = (float*)alloc(131072L * 4);        // sumsq -> invnorm (y path)
  float* xq_raw = (float*)alloc(8192L * 768 * 4);    // reused as r (residual) later
  float* xq_f   = (float*)alloc(8192L * 768 * 4);
  unsigned short* xq_b = (unsigned short*)alloc(8192L * 768 * 2);
  unsigned short* z_b  = (unsigned short*)alloc(131072L * 768 * 2);
  unsigned short* q_b  = (unsigned short*)alloc(8192L * 768 * 2);
  unsigned short* qk_b = (unsigned short*)alloc(8192L * 9216 * 2);  // also u (aliased)
  unsigned short* o_b  = (unsigned short*)alloc(8192L * 768 * 2);
  float* r_f = xq_raw;
  (void)ws_size; (void)in_sizes; (void)n_in; (void)out_size;

  hipMemsetAsync(ssx, 0, 8192L * 4, stream);
  hipMemsetAsync(ssy, 0, 131072L * 4, stream);

  f2b_kernel<<<4608, 256, 0, stream>>>(Wx, Wx_b, 768L * 1536);
  f2b_kernel<<<3072, 256, 0, stream>>>(Wy, Wy_b, 768L * 1024);
  f2b_kernel<<<2304, 256, 0, stream>>>(ipw, Wq_b, 589824);               // Wq
  wkT_kernel<<<2304, 256, 0, stream>>>(ipw, WkT_b);                      // Wk^T per head
  f2b_kernel<<<2304, 256, 0, stream>>>(ipw + 2 * 589824, Wv_b, 589824);  // Wv
  f2b_kernel<<<2304, 256, 0, stream>>>(Wo, Wo_b, 589824);

  // xq_raw = x @ Wx^T + bx   (+ row sumsq)
  gemm_bt<128, 128, true, EPI_F32_SUMSQ, false><<<dim3(64, 6, 1), 256, 0, stream>>>(
      x, (const short*)Wx_b, xq_raw, bx, nullptr, ssx,
      1536, 1536, 768, 1536, 1.f, 0, 0, 0, 0);
  invnorm_kernel<<<32, 256, 0, stream>>>(ssx, 8192);
  xqnorm_kernel<<<24576, 256, 0, stream>>>(xq_raw, ssx, xq_f, xq_b);

  // z = y @ Wy^T + by (bf16) + row sumsq -> invnorm (l2n applied downstream)
  // SWAPXY: 6 column-blocks of one row-panel are adjacent -> A panel L2/L3 reuse
  gemm_bt<128, 128, true, EPI_BF16_SUMSQ, true><<<dim3(6, 1024, 1), 256, 0, stream>>>(
      y, (const short*)Wy_b, z_b, by, nullptr, ssy,
      1024, 1024, 768, 1024, 1.f, 0, 0, 0, 0);
  invnorm_kernel<<<512, 256, 0, stream>>>(ssy, 131072);

  // q = xq @ Wq^T + bq
  gemm_bt<128, 128, false, EPI_BF16, false><<<dim3(64, 6, 1), 256, 0, stream>>>(
      xq_b, (const short*)Wq_b, q_b, ipb, nullptr, nullptr,
      768, 768, 768, 768, 1.f, 0, 0, 0, 0);

  // qk[m,h,:] = scale * q[m,h*64:+64] @ WkT[h]   (bk dropped: softmax-invariant)
  gemm_bt<128, 128, false, EPI_BF16, false><<<dim3(64, 6, 12), 256, 0, stream>>>(
      q_b, (const short*)WkT_b, qk_b, nullptr, nullptr, nullptr,
      768, 64, 9216, 64, 0.125f, 64, 49152, 768, 0);

  // fused scores/softmax/u  (u overwrites qk slice per token)
  attn_kernel<<<8192, 256, 0, stream>>>(z_b, qk_b, ssy, qk_b);

  // o[:,h*64:+64] = u[:,h,:] @ Wv_h^T + bv_h
  gemm_bt<128, 64, false, EPI_BF16, false><<<dim3(64, 1, 12), 256, 0, stream>>>(
      qk_b, (const short*)Wv_b, o_b, ipb + 1536, nullptr, nullptr,
      9216, 768, 768, 768, 1.f, 768, 49152, 64, 64);

  // r = o @ out_w^T + out_b + xq
  gemm_bt<128, 128, false, EPI_F32_RESID, false><<<dim3(64, 6, 1), 256, 0, stream>>>(
      o_b, (const short*)Wo_b, r_f, ob, xq_f, nullptr,
      768, 768, 768, 768, 1.f, 0, 0, 0, 0);

  ln_kernel<<<8192, 256, 0, stream>>>(r_f, lnw, lnb, out);
}

// Round 3
// 888.400 us; speedup vs baseline: 1.7856x; 1.4995x over previous
//
#include <hip/hip_runtime.h>

typedef __attribute__((ext_vector_type(8))) short short8;
typedef __attribute__((ext_vector_type(4))) float f32x4;

static __device__ __forceinline__ float b2f(unsigned short u) {
  return __uint_as_float(((unsigned int)u) << 16);
}
static __device__ __forceinline__ unsigned short f2bs(float f) {
  unsigned int u = __float_as_uint(f);
  u = u + 0x7FFFu + ((u >> 16) & 1u);   // RNE (no NaN inputs here)
  return (unsigned short)(u >> 16);
}

enum { EPI_F32_SUMSQ = 0, EPI_BF16_SUMSQ = 1, EPI_BF16 = 2, EPI_F32_RESID = 3 };

// C[M,N] = A[M,K] @ B[N,K]^T (both K-contiguous). bf16 MFMA 16x16x32.
// BM x BN tile, BK=64, 4 waves (2x2). XOR-swizzled LDS (conflict-free).
// Reg-staged prefetch: tile k+1 global loads issued during tile-k MFMA.
// XCD1D: 1D grid, col-blocks of one row panel share an XCD's L2.
template<int BM, int BN, bool AF32, int EPI, bool XCD1D>
__global__ __launch_bounds__(256, 3) void gemm_bt(
    const void* __restrict__ Av, const short* __restrict__ B, void* __restrict__ Cv,
    const float* __restrict__ bias, const float* __restrict__ resid,
    float* __restrict__ sumsq,
    long lda, long ldb, long ldc, int K, float escale,
    long aZ, long bZ, long cZ, int biasZ, int ncolb)
{
  constexpr int BK = 64;
  constexpr int WM = BM / 2, WN = BN / 2, MR = WM / 16, NR = WN / 16;
  __shared__ __align__(16) short As[BM * BK];
  __shared__ __align__(16) short Bs[BN * BK];
  const int t = threadIdx.x;
  const int zb = blockIdx.z;
  long bxc, byp;
  if constexpr (XCD1D) {
    int bid = blockIdx.x;
    int per = gridDim.x >> 3;       // blocks per XCD (grid % 8 == 0)
    int ppx = per / ncolb;          // row panels per XCD
    int xcd = bid & 7, j = bid >> 3;
    byp = (long)xcd * ppx + j / ncolb;
    bxc = j % ncolb;
  } else {
    byp = blockIdx.x; bxc = blockIdx.y;
  }
  const long row0 = byp * BM;
  const long col0 = bxc * BN;
  const int wave = t >> 6, lane = t & 63;
  const int wr = wave >> 1, wc = wave & 1;
  const int lr = lane & 15, lg = lane >> 4;
  const short* Bz = B + (size_t)zb * bZ;

  float4 pa[BM / 32][2];   // fp32 A staging
  short8 ra[BM / 32];      // bf16 A staging
  short8 rb[BN / 32];      // B staging

  auto loadAB = [&](int k0) {
    #pragma unroll
    for (int r = 0; r < BM / 32; ++r) {
      int e = r * 2048 + t * 8; int row = e >> 6, col = e & 63;
      if constexpr (AF32) {
        const float* src = (const float*)Av + (size_t)zb * aZ +
                           (size_t)(row0 + row) * lda + k0 + col;
        pa[r][0] = *(const float4*)src;
        pa[r][1] = *(const float4*)(src + 4);
      } else {
        ra[r] = *(const short8*)((const short*)Av + (size_t)zb * aZ +
                                 (size_t)(row0 + row) * lda + k0 + col);
      }
    }
    #pragma unroll
    for (int r = 0; r < BN / 32; ++r) {
      int e = r * 2048 + t * 8; int row = e >> 6, col = e & 63;
      rb[r] = *(const short8*)(Bz + (size_t)(col0 + row) * ldb + k0 + col);
    }
  };
  auto writeAB = [&]() {
    #pragma unroll
    for (int r = 0; r < BM / 32; ++r) {
      int e = r * 2048 + t * 8; int row = e >> 6, col = e & 63;
      short8 o;
      if constexpr (AF32) {
        o[0] = (short)f2bs(pa[r][0].x); o[1] = (short)f2bs(pa[r][0].y);
        o[2] = (short)f2bs(pa[r][0].z); o[3] = (short)f2bs(pa[r][0].w);
        o[4] = (short)f2bs(pa[r][1].x); o[5] = (short)f2bs(pa[r][1].y);
        o[6] = (short)f2bs(pa[r][1].z); o[7] = (short)f2bs(pa[r][1].w);
      } else {
        o = ra[r];
      }
      *(short8*)&As[row * BK + (col ^ ((row & 7) << 3))] = o;
    }
    #pragma unroll
    for (int r = 0; r < BN / 32; ++r) {
      int e = r * 2048 + t * 8; int row = e >> 6, col = e & 63;
      *(short8*)&Bs[row * BK + (col ^ ((row & 7) << 3))] = rb[r];
    }
  };

  const f32x4 zero4 = {0.f, 0.f, 0.f, 0.f};
  f32x4 acc[MR][NR];
  #pragma unroll
  for (int m = 0; m < MR; ++m)
    #pragma unroll
    for (int n = 0; n < NR; ++n) acc[m][n] = zero4;

  loadAB(0);
  const int nk = K / BK;
  for (int kt = 0; kt < nk; ++kt) {
    if (kt) __syncthreads();     // LDS free (compute kt-1 done)
    writeAB();                   // stage tile kt (implicit vmcnt wait)
    __syncthreads();             // LDS ready
    if (kt + 1 < nk) loadAB((kt + 1) * BK);  // in flight across MFMA phase
    #pragma unroll
    for (int kk = 0; kk < 2; ++kk) {
      short8 a[MR], b[NR];
      #pragma unroll
      for (int m = 0; m < MR; ++m) {
        int row = wr * WM + m * 16 + lr, col = kk * 32 + lg * 8;
        a[m] = *(const short8*)&As[row * BK + (col ^ ((row & 7) << 3))];
      }
      #pragma unroll
      for (int n = 0; n < NR; ++n) {
        int row = wc * WN + n * 16 + lr, col = kk * 32 + lg * 8;
        b[n] = *(const short8*)&Bs[row * BK + (col ^ ((row & 7) << 3))];
      }
      #pragma unroll
      for (int m = 0; m < MR; ++m)
        #pragma unroll
        for (int n = 0; n < NR; ++n)
          acc[m][n] = __builtin_amdgcn_mfma_f32_16x16x32_bf16(a[m], b[n], acc[m][n], 0, 0, 0);
    }
  }

  const float* biasz = bias ? (bias + (size_t)zb * biasZ) : nullptr;
  float* Cf = (float*)Cv;
  unsigned short* Cb = (unsigned short*)Cv;
  #pragma unroll
  for (int m = 0; m < MR; ++m) {
    #pragma unroll
    for (int i = 0; i < 4; ++i) {
      long row = row0 + wr * WM + m * 16 + lg * 4 + i;
      float sq = 0.f;
      #pragma unroll
      for (int n = 0; n < NR; ++n) {
        long col = col0 + wc * WN + n * 16 + lr;
        float v = acc[m][n][i];
        if (biasz) v += biasz[col];
        v *= escale;
        size_t ci = (size_t)zb * cZ + (size_t)row * ldc + col;
        if constexpr (EPI == EPI_F32_RESID) {
          v += resid[(size_t)row * ldc + col];
          Cf[ci] = v;
        } else if constexpr (EPI == EPI_F32_SUMSQ) {
          Cf[ci] = v;
        } else {
          Cb[ci] = f2bs(v);
        }
        sq += v * v;
      }
      if constexpr (EPI == EPI_F32_SUMSQ || EPI == EPI_BF16_SUMSQ) {
        #pragma unroll
        for (int off = 1; off < 16; off <<= 1) sq += __shfl_xor(sq, off);
        if (lr == 0) atomicAdd(&sumsq[row], sq);
      }
    }
  }
}

__global__ __launch_bounds__(256) void f2b_kernel(const float* __restrict__ s,
                                                  unsigned short* __restrict__ d, long n) {
  long i = (long)blockIdx.x * 256 + threadIdx.x;
  if (i < n) d[i] = f2bs(s[i]);
}

// WkT[h][n][j] = Wk[h*64+j][n],  Wk = in_proj_w rows 768..1535
__global__ __launch_bounds__(256) void wkT_kernel(const float* __restrict__ ipw,
                                                  unsigned short* __restrict__ d) {
  long i = (long)blockIdx.x * 256 + threadIdx.x;
  if (i < 589824) {
    int h = (int)(i / 49152), r = (int)(i % 49152);
    int nn = r >> 6, j = r & 63;
    d[i] = f2bs(ipw[(size_t)(768 + h * 64 + j) * 768 + nn]);
  }
}

__global__ __launch_bounds__(256) void invnorm_kernel(float* s, int n) {
  int i = blockIdx.x * 256 + threadIdx.x;
  if (i < n) s[i] = 1.f / (sqrtf(s[i]) + 1e-6f);
}

__global__ __launch_bounds__(256) void xqnorm_kernel(const float* __restrict__ raw,
                                                     const float* __restrict__ invn,
                                                     float* __restrict__ xf,
                                                     unsigned short* __restrict__ xb) {
  long i = (long)blockIdx.x * 256 + threadIdx.x;  // 8192*768
  int row = (int)(i / 768);
  float v = raw[i] * invn[row];
  xf[i] = v;
  xb[i] = f2bs(v);
}

// Per-token fused: S = (qk . z)*invn -> softmax_w -> a = attn*invn -> u = a @ z
// QK^T on MFMA (K=768 split over 4 waves), PV vectorized short8 (conflict-free).
// u may alias qk (qk slice fully staged to LDS before write).
__global__ __launch_bounds__(256) void attn_kernel(
    const unsigned short* __restrict__ z, const unsigned short* __restrict__ qk,
    const float* __restrict__ invn, unsigned short* __restrict__ u)
{
  __shared__ __align__(16) unsigned short zl[16 * 768];
  __shared__ __align__(16) unsigned short ql[16 * 768];  // rows 12..15 unused
  __shared__ float sc[3][256];
  __shared__ float al[256];
  __shared__ float il[16];
  const int t = threadIdx.x;
  const long m = blockIdx.x;
  const int wv = t >> 6, lane = t & 63;
  const int lr = lane & 15, lg = lane >> 4;

  // stage (granule-XOR swizzle: 16B granule g stored at g ^ (row&7))
  for (int s = t; s < 1536; s += 256) {
    int row = s / 96, g = s % 96;
    *(short8*)&zl[row * 768 + ((g ^ (row & 7)) << 3)] =
        *(const short8*)(z + m * 12288 + (size_t)s * 8);
  }
  for (int s = t; s < 1152; s += 256) {
    int row = s / 96, g = s % 96;
    *(short8*)&ql[row * 768 + ((g ^ (row & 7)) << 3)] =
        *(const short8*)(qk + m * 9216 + (size_t)s * 8);
  }
  if (t < 16) il[t] = invn[m * 16 + t];
  __syncthreads();

  // QK^T: S[h][w] = sum_k ql[h][k] * zl[w][k]; wave wv covers k in [wv*192, +192)
  f32x4 c = {0.f, 0.f, 0.f, 0.f};
  #pragma unroll
  for (int i = 0; i < 6; ++i) {
    int gb = wv * 24 + i * 4 + lg;   // 16B granule index along K
    short8 a = *(const short8*)&ql[lr * 768 + ((gb ^ (lr & 7)) << 3)];
    short8 b = *(const short8*)&zl[lr * 768 + ((gb ^ (lr & 7)) << 3)];
    c = __builtin_amdgcn_mfma_f32_16x16x32_bf16(a, b, c, 0, 0, 0);
  }
  if (wv > 0) {
    #pragma unroll
    for (int i = 0; i < 4; ++i) sc[wv - 1][(lg * 4 + i) * 16 + lr] = c[i];
  }
  __syncthreads();
  if (wv == 0) {
    // lane holds S[h=lg*4+i][w=lr]; softmax over w (16-lane shfl)
    #pragma unroll
    for (int i = 0; i < 4; ++i) {
      int idx = (lg * 4 + i) * 16 + lr;
      float s = (c[i] + sc[0][idx] + sc[1][idx] + sc[2][idx]) * il[lr];
      float mx = s;
      #pragma unroll
      for (int off = 1; off < 16; off <<= 1) mx = fmaxf(mx, __shfl_xor(mx, off));
      float e = __expf(s - mx);
      float sum = e;
      #pragma unroll
      for (int off = 1; off < 16; off <<= 1) sum += __shfl_xor(sum, off);
      al[idx] = e / sum * il[lr];
    }
  }
  __syncthreads();

  // PV: u[h][d0..d0+8) = sum_w al[h*16+w] * zl[w][d0..]
  for (int s = t; s < 1152; s += 256) {
    int h = s / 96, gd = s % 96;
    float acc[8] = {0.f, 0.f, 0.f, 0.f, 0.f, 0.f, 0.f, 0.f};
    #pragma unroll
    for (int w = 0; w < 16; ++w) {
      float aw = al[h * 16 + w];
      short8 zz = *(const short8*)&zl[w * 768 + ((gd ^ (w & 7)) << 3)];
      #pragma unroll
      for (int j = 0; j < 8; ++j) acc[j] += aw * b2f((unsigned short)zz[j]);
    }
    short8 o;
    #pragma unroll
    for (int j = 0; j < 8; ++j) o[j] = (short)f2bs(acc[j]);
    *(short8*)&u[m * 9216 + (size_t)s * 8] = o;
  }
}

__global__ __launch_bounds__(256) void ln_kernel(const float* __restrict__ R,
                                                 const float* __restrict__ w,
                                                 const float* __restrict__ b,
                                                 float* __restrict__ out) {
  const long row = blockIdx.x;
  const int t = threadIdx.x;
  const float* rr = R + row * 768;
  float v0 = rr[t], v1 = rr[t + 256], v2 = rr[t + 512];
  float s = v0 + v1 + v2;
  #pragma unroll
  for (int off = 1; off < 64; off <<= 1) s += __shfl_xor(s, off);
  __shared__ float ps[4];
  __shared__ float ps2[4];
  const int wave = t >> 6, lane = t & 63;
  if (lane == 0) ps[wave] = s;
  __syncthreads();
  const float mean = (ps[0] + ps[1] + ps[2] + ps[3]) * (1.f / 768.f);
  const float d0 = v0 - mean, d1 = v1 - mean, d2 = v2 - mean;
  float q = d0 * d0 + d1 * d1 + d2 * d2;
  #pragma unroll
  for (int off = 1; off < 64; off <<= 1) q += __shfl_xor(q, off);
  if (lane == 0) ps2[wave] = q;
  __syncthreads();
  const float var = (ps2[0] + ps2[1] + ps2[2] + ps2[3]) * (1.f / 768.f);
  const float rs = rsqrtf(var + 1e-6f);
  float* oo = out + row * 768;
  oo[t]       = d0 * rs * w[t]       + b[t];
  oo[t + 256] = d1 * rs * w[t + 256] + b[t + 256];
  oo[t + 512] = d2 * rs * w[t + 512] + b[t + 512];
}

extern "C" void kernel_launch(void* const* d_in, const int* in_sizes, int n_in,
                              void* d_out, int out_size, void* d_ws, size_t ws_size,
                              hipStream_t stream) {
  const float* x   = (const float*)d_in[0];   // (8,1024,1536)
  const float* y   = (const float*)d_in[1];   // (8,16384,1024)
  const float* Wx  = (const float*)d_in[2];   // (768,1536)
  const float* bx  = (const float*)d_in[3];
  const float* Wy  = (const float*)d_in[4];   // (768,1024)
  const float* by  = (const float*)d_in[5];
  const float* ipw = (const float*)d_in[6];   // (2304,768)
  const float* ipb = (const float*)d_in[7];
  const float* Wo  = (const float*)d_in[8];   // (768,768)
  const float* ob  = (const float*)d_in[9];
  const float* lnw = (const float*)d_in[10];
  const float* lnb = (const float*)d_in[11];
  float* out = (float*)d_out;

  char* ws = (char*)d_ws;
  size_t off = 0;
  auto alloc = [&](size_t bytes) {
    void* p = ws + off;
    off += (bytes + 4095) & ~(size_t)4095;
    return p;
  };
  unsigned short* Wx_b  = (unsigned short*)alloc(768L * 1536 * 2);
  unsigned short* Wy_b  = (unsigned short*)alloc(768L * 1024 * 2);
  unsigned short* Wq_b  = (unsigned short*)alloc(768L * 768 * 2);
  unsigned short* WkT_b = (unsigned short*)alloc(768L * 768 * 2);
  unsigned short* Wv_b  = (unsigned short*)alloc(768L * 768 * 2);
  unsigned short* Wo_b  = (unsigned short*)alloc(768L * 768 * 2);
  float* ssx    = (float*)alloc(8192L * 4);          // sumsq -> invnorm (x path)
  float* ssy    = (float*)alloc(131072L * 4);        // sumsq -> invnorm (y path)
  float* xq_raw = (float*)alloc(8192L * 768 * 4);    // reused as r (residual) later
  float* xq_f   = (float*)alloc(8192L * 768 * 4);
  unsigned short* xq_b = (unsigned short*)alloc(8192L * 768 * 2);
  unsigned short* z_b  = (unsigned short*)alloc(131072L * 768 * 2);
  unsigned short* q_b  = (unsigned short*)alloc(8192L * 768 * 2);
  unsigned short* qk_b = (unsigned short*)alloc(8192L * 9216 * 2);  // also u (aliased)
  unsigned short* o_b  = (unsigned short*)alloc(8192L * 768 * 2);
  float* r_f = xq_raw;
  (void)ws_size; (void)in_sizes; (void)n_in; (void)out_size;

  hipMemsetAsync(ssx, 0, 8192L * 4, stream);
  hipMemsetAsync(ssy, 0, 131072L * 4, stream);

  f2b_kernel<<<4608, 256, 0, stream>>>(Wx, Wx_b, 768L * 1536);
  f2b_kernel<<<3072, 256, 0, stream>>>(Wy, Wy_b, 768L * 1024);
  f2b_kernel<<<2304, 256, 0, stream>>>(ipw, Wq_b, 589824);               // Wq
  wkT_kernel<<<2304, 256, 0, stream>>>(ipw, WkT_b);                      // Wk^T per head
  f2b_kernel<<<2304, 256, 0, stream>>>(ipw + 2 * 589824, Wv_b, 589824);  // Wv
  f2b_kernel<<<2304, 256, 0, stream>>>(Wo, Wo_b, 589824);

  // xq_raw = x @ Wx^T + bx   (+ row sumsq)
  gemm_bt<128, 128, true, EPI_F32_SUMSQ, false><<<dim3(64, 6, 1), 256, 0, stream>>>(
      x, (const short*)Wx_b, xq_raw, bx, nullptr, ssx,
      1536, 1536, 768, 1536, 1.f, 0, 0, 0, 0, 0);
  invnorm_kernel<<<32, 256, 0, stream>>>(ssx, 8192);
  xqnorm_kernel<<<24576, 256, 0, stream>>>(xq_raw, ssx, xq_f, xq_b);

  // z = y @ Wy^T + by (bf16) + row sumsq; XCD-contiguous row panels
  gemm_bt<128, 128, true, EPI_BF16_SUMSQ, true><<<6144, 256, 0, stream>>>(
      y, (const short*)Wy_b, z_b, by, nullptr, ssy,
      1024, 1024, 768, 1024, 1.f, 0, 0, 0, 0, 6);
  invnorm_kernel<<<512, 256, 0, stream>>>(ssy, 131072);

  // q = xq @ Wq^T + bq
  gemm_bt<128, 128, false, EPI_BF16, false><<<dim3(64, 6, 1), 256, 0, stream>>>(
      xq_b, (const short*)Wq_b, q_b, ipb, nullptr, nullptr,
      768, 768, 768, 768, 1.f, 0, 0, 0, 0, 0);

  // qk[m,h,:] = scale * q[m,h*64:+64] @ WkT[h]   (bk dropped: softmax-invariant)
  gemm_bt<128, 128, false, EPI_BF16, false><<<dim3(64, 6, 12), 256, 0, stream>>>(
      q_b, (const short*)WkT_b, qk_b, nullptr, nullptr, nullptr,
      768, 64, 9216, 64, 0.125f, 64, 49152, 768, 0, 0);

  // fused scores/softmax/u  (u overwrites qk slice per token)
  attn_kernel<<<8192, 256, 0, stream>>>(z_b, qk_b, ssy, qk_b);

  // o[:,h*64:+64] = u[:,h,:] @ Wv_h^T + bv_h
  gemm_bt<128, 64, false, EPI_BF16, false><<<dim3(64, 1, 12), 256, 0, stream>>>(
      qk_b, (const short*)Wv_b, o_b, ipb + 1536, nullptr, nullptr,
      9216, 768, 768, 768, 1.f, 768, 49152, 64, 64, 0);

  // r = o @ out_w^T + out_b + xq
  gemm_bt<128, 128, false, EPI_F32_RESID, false><<<dim3(64, 6, 1), 256, 0, stream>>>(
      o_b, (const short*)Wo_b, r_f, ob, xq_f, nullptr,
      768, 768, 768, 768, 1.f, 0, 0, 0, 0, 0);

  ln_kernel<<<8192, 256, 0, stream>>>(r_f, lnw, lnb, out);
}